// Round 3
// baseline (2946.027 us; speedup 1.0000x reference)
//
#include <hip/hip_runtime.h>
#include <math.h>

#define D 64
#define RU 256

typedef short bf16x8 __attribute__((ext_vector_type(8)));
typedef float f32x4 __attribute__((ext_vector_type(4)));

__device__ __forceinline__ float selu_f(float x) {
    // scale = 1.0507009873554805, scale*alpha = 1.7580993408473766
    return x > 0.0f ? 1.0507009873554805f * x
                    : 1.7580993408473766f * (__expf(x) - 1.0f);
}

__device__ __forceinline__ short f2bf_rtne(float x) {
    union { float f; unsigned u; } v; v.f = x;
    unsigned r = (v.u + 0x7FFFu + ((v.u >> 16) & 1u)) >> 16;
    return (short)r;
}
__device__ __forceinline__ short f2bf_trunc(float x) {
    union { float f; unsigned u; } v; v.f = x;
    return (short)(v.u >> 16);
}
__device__ __forceinline__ float bf2f(short s) {
    union { float f; unsigned u; } v; v.u = ((unsigned)(unsigned short)s) << 16;
    return v.f;
}

// ---------------- sort setup (once per launch) ----------------

__global__ __launch_bounds__(256) void hist_kernel(
    const int* __restrict__ second, int* __restrict__ counts, int n_edges)
{
    for (int e = blockIdx.x * blockDim.x + threadIdx.x; e < n_edges;
         e += gridDim.x * blockDim.x)
        atomicAdd(&counts[second[e]], 1);
}

// exclusive scan of counts[0..n) -> row_ptr[0..n], duplicate into cursor
__global__ __launch_bounds__(1024) void scan_kernel(
    const int* __restrict__ counts, int* __restrict__ row_ptr,
    int* __restrict__ cursor, int n)
{
    __shared__ int wsum[16];
    __shared__ int woff[16];
    __shared__ int s_total;
    __shared__ int s_carry;
    const int tid = threadIdx.x, wave = tid >> 6, lane = tid & 63;
    if (tid == 0) s_carry = 0;
    __syncthreads();
    for (int base = 0; base < n; base += 1024) {
        const int i = base + tid;
        const int x = (i < n) ? counts[i] : 0;
        int v = x;
#pragma unroll
        for (int off = 1; off < 64; off <<= 1) {
            int t = __shfl_up(v, off, 64);
            if (lane >= off) v += t;
        }
        if (lane == 63) wsum[wave] = v;
        __syncthreads();
        if (wave == 0) {
            int s = (lane < 16) ? wsum[lane] : 0;
#pragma unroll
            for (int off = 1; off < 16; off <<= 1) {
                int t = __shfl_up(s, off, 64);
                if (lane >= off) s += t;
            }
            if (lane < 16) woff[lane] = s - wsum[lane];
            if (lane == 15) s_total = s;
        }
        __syncthreads();
        const int carry = s_carry;
        const int excl = carry + woff[wave] + (v - x);
        if (i < n) { row_ptr[i] = excl; cursor[i] = excl; }
        __syncthreads();
        if (tid == 0) s_carry += s_total;
        __syncthreads();
    }
    if (tid == 0) row_ptr[n] = s_carry;
}

__global__ __launch_bounds__(256) void scatter_kernel(
    const int* __restrict__ first, const int* __restrict__ second,
    int* __restrict__ cursor, int* __restrict__ sfirst,
    int* __restrict__ ssec, int n_edges)
{
    for (int e = blockIdx.x * blockDim.x + threadIdx.x; e < n_edges;
         e += gridDim.x * blockDim.x) {
        const int si = second[e];
        const int pos = atomicAdd(&cursor[si], 1);
        sfirst[pos] = first[e];
        ssec[pos] = si;
    }
}

// ---------------- P/Q via MFMA ----------------
// P = state @ W_msg[0:64,:], Q = state @ W_msg[64:128,:]. Split-bf16.
__global__ __launch_bounds__(256) void pq_mfma_kernel(
    const float* __restrict__ state, const float* __restrict__ W_msg,
    float* __restrict__ P, float* __restrict__ Q, int n_links)
{
    const int tid = threadIdx.x;
    const int wave = tid >> 6;
    const int lane = tid & 63;
    const int m = lane & 15;
    const int qd = lane >> 4;

    // B frags: [mat(P/Q)][ks][jt], k = ks*32 + qd*8 + i, n = jt*16 + m
    bf16x8 Bh[2][2][4], Bl[2][2][4];
#pragma unroll
    for (int mat = 0; mat < 2; ++mat)
#pragma unroll
        for (int ks = 0; ks < 2; ++ks)
#pragma unroll
            for (int jt = 0; jt < 4; ++jt) {
                const int nn = jt * 16 + m;
#pragma unroll
                for (int i = 0; i < 8; ++i) {
                    const int kk = mat * 64 + ks * 32 + qd * 8 + i;
                    const float w = W_msg[kk * 64 + nn];
                    const short hi = f2bf_rtne(w);
                    Bh[mat][ks][jt][i] = hi;
                    Bl[mat][ks][jt][i] = f2bf_rtne(w - bf2f(hi));
                }
            }

    const int ngroups = (n_links + 63) >> 6;
    for (int g = blockIdx.x; g < ngroups; g += gridDim.x) {
        const int base = g * 64 + wave * 16;
        const int l = base + m;
        const bool lv = (l < n_links);
        float xv[16];
        if (lv) {
            const float4* Sr = (const float4*)(state + (size_t)l * D);
            *(float4*)&xv[0]  = Sr[qd * 2];
            *(float4*)&xv[4]  = Sr[qd * 2 + 1];
            *(float4*)&xv[8]  = Sr[8 + qd * 2];
            *(float4*)&xv[12] = Sr[9 + qd * 2];
        } else {
#pragma unroll
            for (int i = 0; i < 16; ++i) xv[i] = 0.0f;
        }
        bf16x8 Ah[2], Al[2];
#pragma unroll
        for (int ks = 0; ks < 2; ++ks)
#pragma unroll
            for (int i = 0; i < 8; ++i) {
                const float v = xv[ks * 8 + i];
                const short hi = f2bf_trunc(v);
                Ah[ks][i] = hi;
                Al[ks][i] = f2bf_trunc(v - bf2f(hi));
            }
        f32x4 accP[4], accQ[4];
#pragma unroll
        for (int jt = 0; jt < 4; ++jt) {
            accP[jt] = (f32x4){0.f, 0.f, 0.f, 0.f};
            accQ[jt] = (f32x4){0.f, 0.f, 0.f, 0.f};
#pragma unroll
            for (int ks = 0; ks < 2; ++ks) {
                accP[jt] = __builtin_amdgcn_mfma_f32_16x16x32_bf16(Ah[ks], Bh[0][ks][jt], accP[jt], 0, 0, 0);
                accP[jt] = __builtin_amdgcn_mfma_f32_16x16x32_bf16(Ah[ks], Bl[0][ks][jt], accP[jt], 0, 0, 0);
                accP[jt] = __builtin_amdgcn_mfma_f32_16x16x32_bf16(Al[ks], Bh[0][ks][jt], accP[jt], 0, 0, 0);
                accQ[jt] = __builtin_amdgcn_mfma_f32_16x16x32_bf16(Ah[ks], Bh[1][ks][jt], accQ[jt], 0, 0, 0);
                accQ[jt] = __builtin_amdgcn_mfma_f32_16x16x32_bf16(Ah[ks], Bl[1][ks][jt], accQ[jt], 0, 0, 0);
                accQ[jt] = __builtin_amdgcn_mfma_f32_16x16x32_bf16(Al[ks], Bh[1][ks][jt], accQ[jt], 0, 0, 0);
            }
        }
        // D layout: row = qd*4 + r (link in tile), col = jt*16 + m (feature)
#pragma unroll
        for (int r = 0; r < 4; ++r) {
            const int lr = base + qd * 4 + r;
            if (lr < n_links) {
#pragma unroll
                for (int jt = 0; jt < 4; ++jt) {
                    P[(size_t)lr * D + jt * 16 + m] = accP[jt][r];
                    Q[(size_t)lr * D + jt * 16 + m] = accQ[jt][r];
                }
            }
        }
    }
}

// ---------------- fused edge kernel (CSR by second, LDS accumulate) ----------
__global__ __launch_bounds__(256) void edge_mfma_v3(
    const float* __restrict__ P, const float* __restrict__ Q,
    const int* __restrict__ sfirst, const int* __restrict__ ssec,
    const int* __restrict__ row_ptr,
    const float* __restrict__ b_msg,
    const float* __restrict__ W_gcn, const float* __restrict__ b_gcn,
    float* __restrict__ S, int n_links)
{
    __shared__ float lacc[64 * 66];
    const int tid = threadIdx.x;
    const int wave = tid >> 6;
    const int lane = tid & 63;
    const int m = lane & 15;
    const int qd = lane >> 4;

    // B fragments of W_gcn (hi/lo) in registers
    bf16x8 Bh[2][4], Bl[2][4];
#pragma unroll
    for (int ks = 0; ks < 2; ++ks)
#pragma unroll
        for (int jt = 0; jt < 4; ++jt) {
            const int nn = jt * 16 + m;
#pragma unroll
            for (int i = 0; i < 8; ++i) {
                const int kk = ks * 32 + qd * 8 + i;
                const float w = W_gcn[kk * 64 + nn];
                const short hi = f2bf_rtne(w);
                Bh[ks][jt][i] = hi;
                Bl[ks][jt][i] = f2bf_rtne(w - bf2f(hi));
            }
        }
    float bias_msg[16];
#pragma unroll
    for (int i = 0; i < 8; ++i) {
        bias_msg[i] = b_msg[qd * 8 + i];
        bias_msg[8 + i] = b_msg[32 + qd * 8 + i];
    }
    float bias_gcn[4];
#pragma unroll
    for (int jt = 0; jt < 4; ++jt) bias_gcn[jt] = b_gcn[jt * 16 + m];

    const int L0 = blockIdx.x * 64;
    const int Lend = min(L0 + 64, n_links);
    const int eb = row_ptr[L0];
    const int ee = row_ptr[Lend];

    for (int i = tid; i < 64 * 66; i += 256) lacc[i] = 0.0f;
    __syncthreads();

    for (int t0 = eb + wave * 16; t0 < ee; t0 += 64) {
        const int e = t0 + m;
        const bool ev = (e < ee);
        int fi = 0, si = L0;
        if (ev) { fi = sfirst[e]; si = ssec[e]; }

        float msg[16];
        if (ev) {
            float pv[16], qv[16];
            const float4* Pr = (const float4*)(P + (size_t)fi * D);
            const float4* Qr = (const float4*)(Q + (size_t)si * D);
            *(float4*)&pv[0]  = Pr[qd * 2];
            *(float4*)&pv[4]  = Pr[qd * 2 + 1];
            *(float4*)&pv[8]  = Pr[8 + qd * 2];
            *(float4*)&pv[12] = Pr[9 + qd * 2];
            *(float4*)&qv[0]  = Qr[qd * 2];
            *(float4*)&qv[4]  = Qr[qd * 2 + 1];
            *(float4*)&qv[8]  = Qr[8 + qd * 2];
            *(float4*)&qv[12] = Qr[9 + qd * 2];
#pragma unroll
            for (int i = 0; i < 16; ++i)
                msg[i] = selu_f(pv[i] + qv[i] + bias_msg[i]);
        } else {
#pragma unroll
            for (int i = 0; i < 16; ++i) msg[i] = 0.0f;
        }

        bf16x8 Ah[2], Al[2];
#pragma unroll
        for (int ks = 0; ks < 2; ++ks)
#pragma unroll
            for (int i = 0; i < 8; ++i) {
                const float v = msg[ks * 8 + i];
                const short hi = f2bf_trunc(v);
                Ah[ks][i] = hi;
                Al[ks][i] = f2bf_trunc(v - bf2f(hi));
            }

        f32x4 acc[4];
#pragma unroll
        for (int jt = 0; jt < 4; ++jt) {
            const float b = bias_gcn[jt];
            acc[jt] = (f32x4){b, b, b, b};
#pragma unroll
            for (int ks = 0; ks < 2; ++ks) {
                acc[jt] = __builtin_amdgcn_mfma_f32_16x16x32_bf16(Ah[ks], Bh[ks][jt], acc[jt], 0, 0, 0);
                acc[jt] = __builtin_amdgcn_mfma_f32_16x16x32_bf16(Ah[ks], Bl[ks][jt], acc[jt], 0, 0, 0);
                acc[jt] = __builtin_amdgcn_mfma_f32_16x16x32_bf16(Al[ks], Bh[ks][jt], acc[jt], 0, 0, 0);
            }
        }

        // accumulate into LDS: row sr-L0, col jt*16+m
#pragma unroll
        for (int r = 0; r < 4; ++r) {
            const int row = qd * 4 + r;
            const int er = t0 + row;
            const int sr = __shfl(si, row, 64);
            if (er < ee) {
                const int lr = sr - L0;
#pragma unroll
                for (int jt = 0; jt < 4; ++jt)
                    atomicAdd(&lacc[lr * 66 + jt * 16 + m], fmaxf(acc[jt][r], 0.0f));
            }
        }
    }
    __syncthreads();

    // write out S rows [L0, Lend) coalesced
    for (int i = tid; i < 64 * 16; i += 256) {
        const int row = i >> 4, c4 = i & 15;
        const int l = L0 + row;
        if (l < n_links) {
            float4 v = *(float4*)&lacc[row * 66 + c4 * 4];
            *(float4*)&S[(size_t)l * D + c4 * 4] = v;
        }
    }
}

// ---------------- readout ----------------

__global__ __launch_bounds__(256) void graph_sum_kernel(
    const float* __restrict__ state, const int* __restrict__ gid,
    float* __restrict__ gemb, int n_links)
{
    const int total = n_links * D;
    for (int idx = blockIdx.x * blockDim.x + threadIdx.x; idx < total;
         idx += gridDim.x * blockDim.x) {
        const int l = idx >> 6;
        const int j = idx & 63;
        atomicAdd(&gemb[gid[l] * D + j], state[idx]);
    }
}

__global__ __launch_bounds__(256) void r1_kernel(
    const float* __restrict__ gemb, const float* __restrict__ W,
    const float* __restrict__ b, float* __restrict__ out)
{
    __shared__ float s[64];
    const int g = blockIdx.x;
    const int j = threadIdx.x;
    if (j < 64) s[j] = gemb[g * D + j];
    __syncthreads();
    float acc = b[j];
#pragma unroll 8
    for (int k = 0; k < 64; ++k) acc += s[k] * W[k * RU + j];
    out[g * RU + j] = selu_f(acc);
}

__global__ __launch_bounds__(256) void r2_kernel(
    const float* __restrict__ rin, const float* __restrict__ W,
    const float* __restrict__ b, float* __restrict__ out)
{
    __shared__ float s[RU];
    const int g = blockIdx.x;
    const int j = threadIdx.x;
    s[j] = rin[g * RU + j];
    __syncthreads();
    float acc = b[j];
#pragma unroll 8
    for (int k = 0; k < RU; ++k) acc += s[k] * W[k * RU + j];
    out[g * RU + j] = selu_f(acc);
}

__global__ __launch_bounds__(256) void r3_kernel(
    const float* __restrict__ rin, const float* __restrict__ W,
    const float* __restrict__ b, float* __restrict__ out)
{
    __shared__ float sW[RU];
    const int g = threadIdx.x;
    sW[g] = W[g];
    __syncthreads();
    float acc = 0.0f;
#pragma unroll 8
    for (int k = 0; k < RU; ++k) acc += rin[g * RU + k] * sW[k];
    out[g] = acc + b[0];
}

extern "C" void kernel_launch(void* const* d_in, const int* in_sizes, int n_in,
                              void* d_out, int out_size, void* d_ws, size_t ws_size,
                              hipStream_t stream)
{
    const float* states_action = (const float*)d_in[0];
    const float* W_msg = (const float*)d_in[1];
    const float* b_msg = (const float*)d_in[2];
    const float* W_gcn = (const float*)d_in[3];
    const float* b_gcn = (const float*)d_in[4];
    const float* W_r1 = (const float*)d_in[5];
    const float* b_r1 = (const float*)d_in[6];
    const float* W_r2 = (const float*)d_in[7];
    const float* b_r2 = (const float*)d_in[8];
    const float* W_r3 = (const float*)d_in[9];
    const float* b_r3 = (const float*)d_in[10];
    const int* gid = (const int*)d_in[11];
    const int* first = (const int*)d_in[12];
    const int* second = (const int*)d_in[13];

    const int n_links = in_sizes[0] / D;     // 100000
    const int n_edges = in_sizes[12];        // 1600000
    const int G = out_size;                  // 256

    const size_t state_bytes = (size_t)n_links * D * sizeof(float);
    char* ws = (char*)d_ws;
    float* S = (float*)ws;                               // 25.6 MB
    float* P = (float*)(ws + state_bytes);               // 25.6 MB
    float* Q = (float*)(ws + 2 * state_bytes);           // 25.6 MB
    char* ws2 = ws + 3 * state_bytes;
    float* gemb = (float*)ws2;           ws2 += (size_t)G * D * sizeof(float);
    float* r1 = (float*)ws2;             ws2 += (size_t)G * RU * sizeof(float);
    float* r2 = (float*)ws2;             ws2 += (size_t)G * RU * sizeof(float);
    int* counts = (int*)ws2;             ws2 += (size_t)(n_links + 1) * sizeof(int);
    int* row_ptr = (int*)ws2;            ws2 += (size_t)(n_links + 1) * sizeof(int);
    int* cursor = (int*)ws2;             ws2 += (size_t)(n_links + 1) * sizeof(int);
    int* sfirst = (int*)ws2;             ws2 += (size_t)n_edges * sizeof(int);
    int* ssec = (int*)ws2;               ws2 += (size_t)n_edges * sizeof(int);

    const int link_blocks = (n_links + 63) / 64;         // 1563

    // ---- sort setup (fixed indices; rebuilt every launch) ----
    hipMemsetAsync(counts, 0, (size_t)(n_links + 1) * sizeof(int), stream);
    hist_kernel<<<512, 256, 0, stream>>>(second, counts, n_edges);
    scan_kernel<<<1, 1024, 0, stream>>>(counts, row_ptr, cursor, n_links);
    scatter_kernel<<<512, 256, 0, stream>>>(first, second, cursor, sfirst, ssec, n_edges);

    // ---- T = 4 message-passing iterations ----
    const float* state_in = states_action;
    for (int t = 0; t < 4; ++t) {
        pq_mfma_kernel<<<784, 256, 0, stream>>>(state_in, W_msg, P, Q, n_links);
        edge_mfma_v3<<<link_blocks, 256, 0, stream>>>(P, Q, sfirst, ssec, row_ptr,
                                                      b_msg, W_gcn, b_gcn, S, n_links);
        state_in = S;
    }

    // ---- readout ----
    hipMemsetAsync(gemb, 0, (size_t)G * D * sizeof(float), stream);
    graph_sum_kernel<<<2048, 256, 0, stream>>>(S, gid, gemb, n_links);
    r1_kernel<<<G, 256, 0, stream>>>(gemb, W_r1, b_r1, r1);
    r2_kernel<<<G, 256, 0, stream>>>(r1, W_r2, b_r2, r2);
    r3_kernel<<<1, 256, 0, stream>>>(r2, W_r3, b_r3, (float*)d_out);
}

// Round 4
// 1618.599 us; speedup vs baseline: 1.8201x; 1.8201x over previous
//
#include <hip/hip_runtime.h>
#include <math.h>

#define D 64
#define RU 256

typedef short bf16x8 __attribute__((ext_vector_type(8)));
typedef float f32x4 __attribute__((ext_vector_type(4)));

__device__ __forceinline__ float selu_f(float x) {
    return x > 0.0f ? 1.0507009873554805f * x
                    : 1.7580993408473766f * (__expf(x) - 1.0f);
}

__device__ __forceinline__ short f2bf_rtne(float x) {
    union { float f; unsigned u; } v; v.f = x;
    unsigned r = (v.u + 0x7FFFu + ((v.u >> 16) & 1u)) >> 16;
    return (short)r;
}
__device__ __forceinline__ short f2bf_trunc(float x) {
    union { float f; unsigned u; } v; v.f = x;
    return (short)(v.u >> 16);
}
__device__ __forceinline__ float bf2f(short s) {
    union { float f; unsigned u; } v; v.u = ((unsigned)(unsigned short)s) << 16;
    return v.f;
}

// ---------------- CSR setup (once per launch) ----------------

__global__ __launch_bounds__(256) void hist_kernel(
    const int* __restrict__ keys, int* __restrict__ counts, int n)
{
    for (int e = blockIdx.x * blockDim.x + threadIdx.x; e < n;
         e += gridDim.x * blockDim.x)
        atomicAdd(&counts[keys[e]], 1);
}

// exclusive scan of counts[0..n) -> row_ptr[0..n], duplicate into cursor
__global__ __launch_bounds__(1024) void scan_kernel(
    const int* __restrict__ counts, int* __restrict__ row_ptr,
    int* __restrict__ cursor, int n)
{
    __shared__ int wsum[16];
    __shared__ int woff[16];
    __shared__ int s_total;
    __shared__ int s_carry;
    const int tid = threadIdx.x, wave = tid >> 6, lane = tid & 63;
    if (tid == 0) s_carry = 0;
    __syncthreads();
    for (int base = 0; base < n; base += 1024) {
        const int i = base + tid;
        const int x = (i < n) ? counts[i] : 0;
        int v = x;
#pragma unroll
        for (int off = 1; off < 64; off <<= 1) {
            int t = __shfl_up(v, off, 64);
            if (lane >= off) v += t;
        }
        if (lane == 63) wsum[wave] = v;
        __syncthreads();
        if (wave == 0) {
            int s = (lane < 16) ? wsum[lane] : 0;
#pragma unroll
            for (int off = 1; off < 16; off <<= 1) {
                int t = __shfl_up(s, off, 64);
                if (lane >= off) s += t;
            }
            if (lane < 16) woff[lane] = s - wsum[lane];
            if (lane == 15) s_total = s;
        }
        __syncthreads();
        const int carry = s_carry;
        const int excl = carry + woff[wave] + (v - x);
        if (i < n) { row_ptr[i] = excl; cursor[i] = excl; }
        __syncthreads();
        if (tid == 0) s_carry += s_total;
        __syncthreads();
    }
    if (tid == 0) row_ptr[n] = s_carry;
}

__global__ __launch_bounds__(256) void scatter_kernel(
    const int* __restrict__ first, const int* __restrict__ second,
    int* __restrict__ cursor, int* __restrict__ sfirst, int n_edges)
{
    for (int e = blockIdx.x * blockDim.x + threadIdx.x; e < n_edges;
         e += gridDim.x * blockDim.x) {
        const int pos = atomicAdd(&cursor[second[e]], 1);
        sfirst[pos] = first[e];
    }
}

// ---------------- P/Q via MFMA ----------------
// P = state @ W_msg[0:64,:], Q = state @ W_msg[64:128,:]. Split-bf16.
__global__ __launch_bounds__(256) void pq_mfma_kernel(
    const float* __restrict__ state, const float* __restrict__ W_msg,
    float* __restrict__ P, float* __restrict__ Q, int n_links)
{
    const int tid = threadIdx.x;
    const int wave = tid >> 6;
    const int lane = tid & 63;
    const int m = lane & 15;
    const int qd = lane >> 4;

    bf16x8 Bh[2][2][4], Bl[2][2][4];
#pragma unroll
    for (int mat = 0; mat < 2; ++mat)
#pragma unroll
        for (int ks = 0; ks < 2; ++ks)
#pragma unroll
            for (int jt = 0; jt < 4; ++jt) {
                const int nn = jt * 16 + m;
#pragma unroll
                for (int i = 0; i < 8; ++i) {
                    const int kk = mat * 64 + ks * 32 + qd * 8 + i;
                    const float w = W_msg[kk * 64 + nn];
                    const short hi = f2bf_rtne(w);
                    Bh[mat][ks][jt][i] = hi;
                    Bl[mat][ks][jt][i] = f2bf_rtne(w - bf2f(hi));
                }
            }

    const int ngroups = (n_links + 63) >> 6;
    for (int g = blockIdx.x; g < ngroups; g += gridDim.x) {
        const int base = g * 64 + wave * 16;
        const int l = base + m;
        const bool lv = (l < n_links);
        float xv[16];
        if (lv) {
            const float4* Sr = (const float4*)(state + (size_t)l * D);
            *(float4*)&xv[0]  = Sr[qd * 2];
            *(float4*)&xv[4]  = Sr[qd * 2 + 1];
            *(float4*)&xv[8]  = Sr[8 + qd * 2];
            *(float4*)&xv[12] = Sr[9 + qd * 2];
        } else {
#pragma unroll
            for (int i = 0; i < 16; ++i) xv[i] = 0.0f;
        }
        bf16x8 Ah[2], Al[2];
#pragma unroll
        for (int ks = 0; ks < 2; ++ks)
#pragma unroll
            for (int i = 0; i < 8; ++i) {
                const float v = xv[ks * 8 + i];
                const short hi = f2bf_trunc(v);
                Ah[ks][i] = hi;
                Al[ks][i] = f2bf_trunc(v - bf2f(hi));
            }
        f32x4 accP[4], accQ[4];
#pragma unroll
        for (int jt = 0; jt < 4; ++jt) {
            accP[jt] = (f32x4){0.f, 0.f, 0.f, 0.f};
            accQ[jt] = (f32x4){0.f, 0.f, 0.f, 0.f};
#pragma unroll
            for (int ks = 0; ks < 2; ++ks) {
                accP[jt] = __builtin_amdgcn_mfma_f32_16x16x32_bf16(Ah[ks], Bh[0][ks][jt], accP[jt], 0, 0, 0);
                accP[jt] = __builtin_amdgcn_mfma_f32_16x16x32_bf16(Ah[ks], Bl[0][ks][jt], accP[jt], 0, 0, 0);
                accP[jt] = __builtin_amdgcn_mfma_f32_16x16x32_bf16(Al[ks], Bh[0][ks][jt], accP[jt], 0, 0, 0);
                accQ[jt] = __builtin_amdgcn_mfma_f32_16x16x32_bf16(Ah[ks], Bh[1][ks][jt], accQ[jt], 0, 0, 0);
                accQ[jt] = __builtin_amdgcn_mfma_f32_16x16x32_bf16(Ah[ks], Bl[1][ks][jt], accQ[jt], 0, 0, 0);
                accQ[jt] = __builtin_amdgcn_mfma_f32_16x16x32_bf16(Al[ks], Bh[1][ks][jt], accQ[jt], 0, 0, 0);
            }
        }
#pragma unroll
        for (int r = 0; r < 4; ++r) {
            const int lr = base + qd * 4 + r;
            if (lr < n_links) {
#pragma unroll
                for (int jt = 0; jt < 4; ++jt) {
                    P[(size_t)lr * D + jt * 16 + m] = accP[jt][r];
                    Q[(size_t)lr * D + jt * 16 + m] = accQ[jt][r];
                }
            }
        }
    }
}

// ---------------- link-centric fused edge kernel ----------------
// One wave per link: gather P[fi] for its CSR edges, Q[l] loaded once,
// selu -> MFMA GCN -> relu -> register row-sum -> single plain store of S[l].
// No LDS, no atomics, no barriers.
__global__ __launch_bounds__(256) void edge_link_kernel(
    const float* __restrict__ P, const float* __restrict__ Q,
    const int* __restrict__ sfirst, const int* __restrict__ row_ptr,
    const float* __restrict__ b_msg,
    const float* __restrict__ W_gcn, const float* __restrict__ b_gcn,
    float* __restrict__ S, int n_links)
{
    const int tid = threadIdx.x;
    const int wave = tid >> 6;
    const int lane = tid & 63;
    const int m = lane & 15;
    const int qd = lane >> 4;

    bf16x8 Bh[2][4], Bl[2][4];
#pragma unroll
    for (int ks = 0; ks < 2; ++ks)
#pragma unroll
        for (int jt = 0; jt < 4; ++jt) {
            const int nn = jt * 16 + m;
#pragma unroll
            for (int i = 0; i < 8; ++i) {
                const int kk = ks * 32 + qd * 8 + i;
                const float w = W_gcn[kk * 64 + nn];
                const short hi = f2bf_rtne(w);
                Bh[ks][jt][i] = hi;
                Bl[ks][jt][i] = f2bf_rtne(w - bf2f(hi));
            }
        }
    float bias_msg[16];
#pragma unroll
    for (int i = 0; i < 8; ++i) {
        bias_msg[i] = b_msg[qd * 8 + i];
        bias_msg[8 + i] = b_msg[32 + qd * 8 + i];
    }
    float bias_gcn[4];
#pragma unroll
    for (int jt = 0; jt < 4; ++jt) bias_gcn[jt] = b_gcn[jt * 16 + m];

    for (int l = blockIdx.x * 4 + wave; l < n_links; l += gridDim.x * 4) {
        const int es = row_ptr[l];
        const int ee = row_ptr[l + 1];

        // Q[l] + b_msg once per link (si == l for every edge here)
        float qb[16];
        {
            const float4* Qr = (const float4*)(Q + (size_t)l * D);
            *(float4*)&qb[0]  = Qr[qd * 2];
            *(float4*)&qb[4]  = Qr[qd * 2 + 1];
            *(float4*)&qb[8]  = Qr[8 + qd * 2];
            *(float4*)&qb[12] = Qr[9 + qd * 2];
#pragma unroll
            for (int i = 0; i < 16; ++i) qb[i] += bias_msg[i];
        }

        float rsum[4] = {0.f, 0.f, 0.f, 0.f};
        for (int eo = es; eo < ee; eo += 16) {
            const int e = eo + m;
            const int fi = sfirst[min(e, ee - 1)];

            float pv[16], msg[16];
            const float4* Pr = (const float4*)(P + (size_t)fi * D);
            *(float4*)&pv[0]  = Pr[qd * 2];
            *(float4*)&pv[4]  = Pr[qd * 2 + 1];
            *(float4*)&pv[8]  = Pr[8 + qd * 2];
            *(float4*)&pv[12] = Pr[9 + qd * 2];
#pragma unroll
            for (int i = 0; i < 16; ++i)
                msg[i] = selu_f(pv[i] + qb[i]);

            bf16x8 Ah[2], Al[2];
#pragma unroll
            for (int ks = 0; ks < 2; ++ks)
#pragma unroll
                for (int i = 0; i < 8; ++i) {
                    const float v = msg[ks * 8 + i];
                    const short hi = f2bf_trunc(v);
                    Ah[ks][i] = hi;
                    Al[ks][i] = f2bf_trunc(v - bf2f(hi));
                }

            f32x4 acc[4];
#pragma unroll
            for (int jt = 0; jt < 4; ++jt) {
                const float b = bias_gcn[jt];
                acc[jt] = (f32x4){b, b, b, b};
#pragma unroll
                for (int ks = 0; ks < 2; ++ks) {
                    acc[jt] = __builtin_amdgcn_mfma_f32_16x16x32_bf16(Ah[ks], Bh[ks][jt], acc[jt], 0, 0, 0);
                    acc[jt] = __builtin_amdgcn_mfma_f32_16x16x32_bf16(Ah[ks], Bl[ks][jt], acc[jt], 0, 0, 0);
                    acc[jt] = __builtin_amdgcn_mfma_f32_16x16x32_bf16(Al[ks], Bh[ks][jt], acc[jt], 0, 0, 0);
                }
            }

            // relu, mask padded rows, accumulate row-sums in registers
#pragma unroll
            for (int jt = 0; jt < 4; ++jt)
#pragma unroll
                for (int r = 0; r < 4; ++r) {
                    const int er = eo + qd * 4 + r;
                    const float h = fmaxf(acc[jt][r], 0.0f);
                    rsum[jt] += (er < ee) ? h : 0.0f;
                }
        }

        // cross-quad reduction: rows live across reg r (done) and quads
#pragma unroll
        for (int jt = 0; jt < 4; ++jt) {
            rsum[jt] += __shfl_xor(rsum[jt], 16, 64);
            rsum[jt] += __shfl_xor(rsum[jt], 32, 64);
        }
        const float outv = (qd == 0) ? rsum[0] : (qd == 1) ? rsum[1]
                         : (qd == 2) ? rsum[2] : rsum[3];
        S[(size_t)l * D + qd * 16 + m] = outv;
    }
}

// ---------------- readout ----------------

// per-graph segment sum via CSR over sorted gid (no atomics)
__global__ __launch_bounds__(256) void gsum_kernel(
    const float* __restrict__ S, const int* __restrict__ grow,
    float* __restrict__ gemb)
{
    __shared__ float red[4][64];
    const int g = blockIdx.x;
    const int slot = threadIdx.x >> 6;
    const int j = threadIdx.x & 63;
    const int ls = grow[g], le = grow[g + 1];
    float acc = 0.0f;
    for (int l = ls + slot; l < le; l += 4)
        acc += S[(size_t)l * D + j];
    red[slot][j] = acc;
    __syncthreads();
    if (slot == 0)
        gemb[g * D + j] = red[0][j] + red[1][j] + red[2][j] + red[3][j];
}

__global__ __launch_bounds__(256) void r1_kernel(
    const float* __restrict__ gemb, const float* __restrict__ W,
    const float* __restrict__ b, float* __restrict__ out)
{
    __shared__ float s[64];
    const int g = blockIdx.x;
    const int j = threadIdx.x;
    if (j < 64) s[j] = gemb[g * D + j];
    __syncthreads();
    float acc = b[j];
#pragma unroll 8
    for (int k = 0; k < 64; ++k) acc += s[k] * W[k * RU + j];
    out[g * RU + j] = selu_f(acc);
}

__global__ __launch_bounds__(256) void r2_kernel(
    const float* __restrict__ rin, const float* __restrict__ W,
    const float* __restrict__ b, float* __restrict__ out)
{
    __shared__ float s[RU];
    const int g = blockIdx.x;
    const int j = threadIdx.x;
    s[j] = rin[g * RU + j];
    __syncthreads();
    float acc = b[j];
#pragma unroll 8
    for (int k = 0; k < RU; ++k) acc += s[k] * W[k * RU + j];
    out[g * RU + j] = selu_f(acc);
}

__global__ __launch_bounds__(256) void r3_kernel(
    const float* __restrict__ rin, const float* __restrict__ W,
    const float* __restrict__ b, float* __restrict__ out)
{
    __shared__ float sW[RU];
    const int g = threadIdx.x;
    sW[g] = W[g];
    __syncthreads();
    float acc = 0.0f;
#pragma unroll 8
    for (int k = 0; k < RU; ++k) acc += rin[g * RU + k] * sW[k];
    out[g] = acc + b[0];
}

extern "C" void kernel_launch(void* const* d_in, const int* in_sizes, int n_in,
                              void* d_out, int out_size, void* d_ws, size_t ws_size,
                              hipStream_t stream)
{
    const float* states_action = (const float*)d_in[0];
    const float* W_msg = (const float*)d_in[1];
    const float* b_msg = (const float*)d_in[2];
    const float* W_gcn = (const float*)d_in[3];
    const float* b_gcn = (const float*)d_in[4];
    const float* W_r1 = (const float*)d_in[5];
    const float* b_r1 = (const float*)d_in[6];
    const float* W_r2 = (const float*)d_in[7];
    const float* b_r2 = (const float*)d_in[8];
    const float* W_r3 = (const float*)d_in[9];
    const float* b_r3 = (const float*)d_in[10];
    const int* gid = (const int*)d_in[11];
    const int* first = (const int*)d_in[12];
    const int* second = (const int*)d_in[13];

    const int n_links = in_sizes[0] / D;     // 100000
    const int n_edges = in_sizes[12];        // 1600000
    const int G = out_size;                  // 256

    const size_t state_bytes = (size_t)n_links * D * sizeof(float);
    char* ws = (char*)d_ws;
    float* S = (float*)ws;                               // 25.6 MB
    float* P = (float*)(ws + state_bytes);               // 25.6 MB
    float* Q = (float*)(ws + 2 * state_bytes);           // 25.6 MB
    char* ws2 = ws + 3 * state_bytes;
    float* gemb = (float*)ws2;           ws2 += (size_t)G * D * sizeof(float);
    float* r1 = (float*)ws2;             ws2 += (size_t)G * RU * sizeof(float);
    float* r2 = (float*)ws2;             ws2 += (size_t)G * RU * sizeof(float);
    int* counts = (int*)ws2;             ws2 += (size_t)(n_links + 1) * sizeof(int);
    int* row_ptr = (int*)ws2;            ws2 += (size_t)(n_links + 1) * sizeof(int);
    int* cursor = (int*)ws2;             ws2 += (size_t)(n_links + 1) * sizeof(int);
    int* gcounts = (int*)ws2;            ws2 += (size_t)(G + 1) * sizeof(int);
    int* grow = (int*)ws2;               ws2 += (size_t)(G + 1) * sizeof(int);
    int* gcur = (int*)ws2;               ws2 += (size_t)(G + 1) * sizeof(int);
    int* sfirst = (int*)ws2;             ws2 += (size_t)n_edges * sizeof(int);

    // ---- CSR setup (indices fixed; rebuilt every launch since ws is poisoned)
    hipMemsetAsync(counts, 0, (size_t)(n_links + 1) * sizeof(int), stream);
    hipMemsetAsync(gcounts, 0, (size_t)(G + 1) * sizeof(int), stream);
    hist_kernel<<<512, 256, 0, stream>>>(second, counts, n_edges);
    hist_kernel<<<512, 256, 0, stream>>>(gid, gcounts, n_links);
    scan_kernel<<<1, 1024, 0, stream>>>(counts, row_ptr, cursor, n_links);
    scan_kernel<<<1, 1024, 0, stream>>>(gcounts, grow, gcur, G);
    scatter_kernel<<<512, 256, 0, stream>>>(first, second, cursor, sfirst, n_edges);

    // ---- T = 4 message-passing iterations ----
    const int link_groups = (n_links + 63) / 64;         // 1563
    const float* state_in = states_action;
    for (int t = 0; t < 4; ++t) {
        pq_mfma_kernel<<<link_groups, 256, 0, stream>>>(state_in, W_msg, P, Q, n_links);
        edge_link_kernel<<<8192, 256, 0, stream>>>(P, Q, sfirst, row_ptr,
                                                   b_msg, W_gcn, b_gcn, S, n_links);
        state_in = S;
    }

    // ---- readout ----
    gsum_kernel<<<G, 256, 0, stream>>>(S, grow, gemb);
    r1_kernel<<<G, 256, 0, stream>>>(gemb, W_r1, b_r1, r1);
    r2_kernel<<<G, 256, 0, stream>>>(r1, W_r2, b_r2, r2);
    r3_kernel<<<1, 256, 0, stream>>>(r2, W_r3, b_r3, (float*)d_out);
}

// Round 5
// 1466.664 us; speedup vs baseline: 2.0087x; 1.1036x over previous
//
#include <hip/hip_runtime.h>
#include <hip/hip_bf16.h>
#include <math.h>

#define D 64
#define RU 256

typedef short bf16x8 __attribute__((ext_vector_type(8)));
typedef float f32x4 __attribute__((ext_vector_type(4)));

__device__ __forceinline__ float selu_f(float x) {
    return x > 0.0f ? 1.0507009873554805f * x
                    : 1.7580993408473766f * (__expf(x) - 1.0f);
}

__device__ __forceinline__ short f2bf_rtne(float x) {
    union { float f; unsigned u; } v; v.f = x;
    unsigned r = (v.u + 0x7FFFu + ((v.u >> 16) & 1u)) >> 16;
    return (short)r;
}
__device__ __forceinline__ float bf2f(short s) {
    union { float f; unsigned u; } v; v.u = ((unsigned)(unsigned short)s) << 16;
    return v.f;
}

// Split 8 floats into hi/lo bf16x8 using packed cvt (v_cvt_pk_bf16_f32).
__device__ __forceinline__ void split_pack8(const float* v, bf16x8* hi, bf16x8* lo) {
    union { bf16x8 v; unsigned u[4]; } H, L;
#pragma unroll
    for (int j = 0; j < 4; ++j) {
        float2 p; p.x = v[2 * j]; p.y = v[2 * j + 1];
        __hip_bfloat162 hb = __float22bfloat162_rn(p);
        unsigned hu = *(unsigned*)&hb;
        H.u[j] = hu;
        union { unsigned u; float f; } e, o;
        e.u = hu << 16;            // f32 of even (low) element
        o.u = hu & 0xffff0000u;    // f32 of odd (high) element
        float2 q; q.x = p.x - e.f; q.y = p.y - o.f;
        __hip_bfloat162 lb = __float22bfloat162_rn(q);
        L.u[j] = *(unsigned*)&lb;
    }
    *hi = H.v; *lo = L.v;
}

// ---------------- CSR setup (once per launch) ----------------

__global__ __launch_bounds__(256) void hist_kernel(
    const int* __restrict__ keys, int* __restrict__ counts, int n)
{
    for (int e = blockIdx.x * blockDim.x + threadIdx.x; e < n;
         e += gridDim.x * blockDim.x)
        atomicAdd(&counts[keys[e]], 1);
}

__global__ __launch_bounds__(1024) void scan_kernel(
    const int* __restrict__ counts, int* __restrict__ row_ptr,
    int* __restrict__ cursor, int n)
{
    __shared__ int wsum[16];
    __shared__ int woff[16];
    __shared__ int s_total;
    __shared__ int s_carry;
    const int tid = threadIdx.x, wave = tid >> 6, lane = tid & 63;
    if (tid == 0) s_carry = 0;
    __syncthreads();
    for (int base = 0; base < n; base += 1024) {
        const int i = base + tid;
        const int x = (i < n) ? counts[i] : 0;
        int v = x;
#pragma unroll
        for (int off = 1; off < 64; off <<= 1) {
            int t = __shfl_up(v, off, 64);
            if (lane >= off) v += t;
        }
        if (lane == 63) wsum[wave] = v;
        __syncthreads();
        if (wave == 0) {
            int s = (lane < 16) ? wsum[lane] : 0;
#pragma unroll
            for (int off = 1; off < 16; off <<= 1) {
                int t = __shfl_up(s, off, 64);
                if (lane >= off) s += t;
            }
            if (lane < 16) woff[lane] = s - wsum[lane];
            if (lane == 15) s_total = s;
        }
        __syncthreads();
        const int carry = s_carry;
        const int excl = carry + woff[wave] + (v - x);
        if (i < n) { row_ptr[i] = excl; cursor[i] = excl; }
        __syncthreads();
        if (tid == 0) s_carry += s_total;
        __syncthreads();
    }
    if (tid == 0) row_ptr[n] = s_carry;
}

__global__ __launch_bounds__(256) void scatter_kernel(
    const int* __restrict__ first, const int* __restrict__ second,
    int* __restrict__ cursor, int* __restrict__ sfirst, int n_edges)
{
    for (int e = blockIdx.x * blockDim.x + threadIdx.x; e < n_edges;
         e += gridDim.x * blockDim.x) {
        const int pos = atomicAdd(&cursor[second[e]], 1);
        sfirst[pos] = first[e];
    }
}

// ---------------- P/Q via MFMA ----------------
__global__ __launch_bounds__(256) void pq_mfma_kernel(
    const float* __restrict__ state, const float* __restrict__ W_msg,
    float* __restrict__ P, float* __restrict__ Q, int n_links)
{
    const int tid = threadIdx.x;
    const int wave = tid >> 6;
    const int lane = tid & 63;
    const int m = lane & 15;
    const int qd = lane >> 4;

    bf16x8 Bh[2][2][4], Bl[2][2][4];
#pragma unroll
    for (int mat = 0; mat < 2; ++mat)
#pragma unroll
        for (int ks = 0; ks < 2; ++ks)
#pragma unroll
            for (int jt = 0; jt < 4; ++jt) {
                const int nn = jt * 16 + m;
#pragma unroll
                for (int i = 0; i < 8; ++i) {
                    const int kk = mat * 64 + ks * 32 + qd * 8 + i;
                    const float w = W_msg[kk * 64 + nn];
                    const short hi = f2bf_rtne(w);
                    Bh[mat][ks][jt][i] = hi;
                    Bl[mat][ks][jt][i] = f2bf_rtne(w - bf2f(hi));
                }
            }

    const int ngroups = (n_links + 63) >> 6;
    for (int g = blockIdx.x; g < ngroups; g += gridDim.x) {
        const int base = g * 64 + wave * 16;
        const int l = base + m;
        const bool lv = (l < n_links);
        float xv[16];
        if (lv) {
            const float4* Sr = (const float4*)(state + (size_t)l * D);
            *(float4*)&xv[0]  = Sr[qd * 2];
            *(float4*)&xv[4]  = Sr[qd * 2 + 1];
            *(float4*)&xv[8]  = Sr[8 + qd * 2];
            *(float4*)&xv[12] = Sr[9 + qd * 2];
        } else {
#pragma unroll
            for (int i = 0; i < 16; ++i) xv[i] = 0.0f;
        }
        bf16x8 Ah[2], Al[2];
        split_pack8(&xv[0], &Ah[0], &Al[0]);
        split_pack8(&xv[8], &Ah[1], &Al[1]);
        f32x4 accP[4], accQ[4];
#pragma unroll
        for (int jt = 0; jt < 4; ++jt) {
            accP[jt] = (f32x4){0.f, 0.f, 0.f, 0.f};
            accQ[jt] = (f32x4){0.f, 0.f, 0.f, 0.f};
#pragma unroll
            for (int ks = 0; ks < 2; ++ks) {
                accP[jt] = __builtin_amdgcn_mfma_f32_16x16x32_bf16(Ah[ks], Bh[0][ks][jt], accP[jt], 0, 0, 0);
                accP[jt] = __builtin_amdgcn_mfma_f32_16x16x32_bf16(Ah[ks], Bl[0][ks][jt], accP[jt], 0, 0, 0);
                accP[jt] = __builtin_amdgcn_mfma_f32_16x16x32_bf16(Al[ks], Bh[0][ks][jt], accP[jt], 0, 0, 0);
                accQ[jt] = __builtin_amdgcn_mfma_f32_16x16x32_bf16(Ah[ks], Bh[1][ks][jt], accQ[jt], 0, 0, 0);
                accQ[jt] = __builtin_amdgcn_mfma_f32_16x16x32_bf16(Ah[ks], Bl[1][ks][jt], accQ[jt], 0, 0, 0);
                accQ[jt] = __builtin_amdgcn_mfma_f32_16x16x32_bf16(Al[ks], Bh[1][ks][jt], accQ[jt], 0, 0, 0);
            }
        }
#pragma unroll
        for (int r = 0; r < 4; ++r) {
            const int lr = base + qd * 4 + r;
            if (lr < n_links) {
#pragma unroll
                for (int jt = 0; jt < 4; ++jt) {
                    P[(size_t)lr * D + jt * 16 + m] = accP[jt][r];
                    Q[(size_t)lr * D + jt * 16 + m] = accQ[jt][r];
                }
            }
        }
    }
}

// ---------------- link-centric fused edge kernel ----------------
// Wave owns CHUNK consecutive links. Zero msg for tail lanes pre-MFMA;
// exact bias correction post-MFMA (invalid rows contribute relu(b_gcn)).
#define CHUNK 2
__global__ __launch_bounds__(256) void edge_link_kernel(
    const float* __restrict__ P, const float* __restrict__ Q,
    const int* __restrict__ sfirst, const int* __restrict__ row_ptr,
    const float* __restrict__ b_msg,
    const float* __restrict__ W_gcn, const float* __restrict__ b_gcn,
    float* __restrict__ S, int n_links)
{
    const int tid = threadIdx.x;
    const int wave = tid >> 6;
    const int lane = tid & 63;
    const int m = lane & 15;
    const int qd = lane >> 4;

    bf16x8 Bh[2][4], Bl[2][4];
#pragma unroll
    for (int ks = 0; ks < 2; ++ks)
#pragma unroll
        for (int jt = 0; jt < 4; ++jt) {
            const int nn = jt * 16 + m;
#pragma unroll
            for (int i = 0; i < 8; ++i) {
                const int kk = ks * 32 + qd * 8 + i;
                const float w = W_gcn[kk * 64 + nn];
                const short hi = f2bf_rtne(w);
                Bh[ks][jt][i] = hi;
                Bl[ks][jt][i] = f2bf_rtne(w - bf2f(hi));
            }
        }
    float bias_msg[16];
#pragma unroll
    for (int i = 0; i < 8; ++i) {
        bias_msg[i] = b_msg[qd * 8 + i];
        bias_msg[8 + i] = b_msg[32 + qd * 8 + i];
    }
    float bias_gcn[4], rb[4];
#pragma unroll
    for (int jt = 0; jt < 4; ++jt) {
        bias_gcn[jt] = b_gcn[jt * 16 + m];
        rb[jt] = fmaxf(bias_gcn[jt], 0.0f);
    }

    const int wid = blockIdx.x * 4 + wave;
    const int l0 = wid * CHUNK;
    const int l1 = min(l0 + CHUNK, n_links);

    for (int l = l0; l < l1; ++l) {
        const int es = row_ptr[l];
        const int ee = row_ptr[l + 1];

        // Q[l] + b_msg once per link (si == l for all its edges)
        float qb[16];
        {
            const float4* Qr = (const float4*)(Q + (size_t)l * D);
            *(float4*)&qb[0]  = Qr[qd * 2];
            *(float4*)&qb[4]  = Qr[qd * 2 + 1];
            *(float4*)&qb[8]  = Qr[8 + qd * 2];
            *(float4*)&qb[12] = Qr[9 + qd * 2];
#pragma unroll
            for (int i = 0; i < 16; ++i) qb[i] += bias_msg[i];
        }

        float rsum[4] = {0.f, 0.f, 0.f, 0.f};
        for (int eo = es; eo < ee; eo += 16) {
            const int e = eo + m;
            const bool ev = (e < ee);
            const int fi = sfirst[min(e, ee - 1)];

            float pv[16], msg[16];
            const float4* Pr = (const float4*)(P + (size_t)fi * D);
            *(float4*)&pv[0]  = Pr[qd * 2];
            *(float4*)&pv[4]  = Pr[qd * 2 + 1];
            *(float4*)&pv[8]  = Pr[8 + qd * 2];
            *(float4*)&pv[12] = Pr[9 + qd * 2];
#pragma unroll
            for (int i = 0; i < 16; ++i)
                msg[i] = ev ? selu_f(pv[i] + qb[i]) : 0.0f;

            bf16x8 Ah[2], Al[2];
            split_pack8(&msg[0], &Ah[0], &Al[0]);
            split_pack8(&msg[8], &Ah[1], &Al[1]);

            f32x4 acc[4];
#pragma unroll
            for (int jt = 0; jt < 4; ++jt) {
                const float b = bias_gcn[jt];
                acc[jt] = (f32x4){b, b, b, b};
#pragma unroll
                for (int ks = 0; ks < 2; ++ks) {
                    acc[jt] = __builtin_amdgcn_mfma_f32_16x16x32_bf16(Ah[ks], Bh[ks][jt], acc[jt], 0, 0, 0);
                    acc[jt] = __builtin_amdgcn_mfma_f32_16x16x32_bf16(Ah[ks], Bl[ks][jt], acc[jt], 0, 0, 0);
                    acc[jt] = __builtin_amdgcn_mfma_f32_16x16x32_bf16(Al[ks], Bh[ks][jt], acc[jt], 0, 0, 0);
                }
            }

            // relu + accumulate; invalid rows contribute exactly relu(b_gcn)
#pragma unroll
            for (int jt = 0; jt < 4; ++jt)
#pragma unroll
                for (int r = 0; r < 4; ++r)
                    rsum[jt] += fmaxf(acc[jt][r], 0.0f);

            const int over = eo + qd * 4 + 4 - ee;           // invalid rows in my quad
            const float cnt = (float)max(0, min(4, over));
#pragma unroll
            for (int jt = 0; jt < 4; ++jt)
                rsum[jt] -= rb[jt] * cnt;
        }

#pragma unroll
        for (int jt = 0; jt < 4; ++jt) {
            rsum[jt] += __shfl_xor(rsum[jt], 16, 64);
            rsum[jt] += __shfl_xor(rsum[jt], 32, 64);
        }
        const float outv = (qd == 0) ? rsum[0] : (qd == 1) ? rsum[1]
                         : (qd == 2) ? rsum[2] : rsum[3];
        S[(size_t)l * D + qd * 16 + m] = outv;
    }
}

// ---------------- fused readout: gsum + r1 + r2 + r3, one block per graph ----
__global__ __launch_bounds__(256) void readout_kernel(
    const float* __restrict__ S, const int* __restrict__ grow,
    const float* __restrict__ W_r1, const float* __restrict__ b_r1,
    const float* __restrict__ W_r2, const float* __restrict__ b_r2,
    const float* __restrict__ W_r3, const float* __restrict__ b_r3,
    float* __restrict__ out)
{
    __shared__ float red[4][64];
    __shared__ float gl[64];
    __shared__ float row1[RU];
    __shared__ float row2[RU];
    __shared__ float fin[4];
    const int g = blockIdx.x;
    const int tid = threadIdx.x;
    const int slot = tid >> 6;
    const int lane = tid & 63;

    // segment sum over this graph's links
    const int ls = grow[g], le = grow[g + 1];
    float acc = 0.0f;
    for (int l = ls + slot; l < le; l += 4)
        acc += S[(size_t)l * D + lane];
    red[slot][lane] = acc;
    __syncthreads();
    if (slot == 0)
        gl[lane] = red[0][lane] + red[1][lane] + red[2][lane] + red[3][lane];
    __syncthreads();

    // r1 = selu(gl @ W_r1 + b_r1)
    float a1 = b_r1[tid];
#pragma unroll 8
    for (int k = 0; k < 64; ++k) a1 += gl[k] * W_r1[k * RU + tid];
    row1[tid] = selu_f(a1);
    __syncthreads();

    // r2 = selu(row1 @ W_r2 + b_r2)
    float a2 = b_r2[tid];
#pragma unroll 8
    for (int k = 0; k < RU; ++k) a2 += row1[k] * W_r2[k * RU + tid];
    row2[tid] = selu_f(a2);
    __syncthreads();

    // r3 = row2 @ W_r3 + b_r3
    float p = row2[tid] * W_r3[tid];
#pragma unroll
    for (int off = 32; off >= 1; off >>= 1)
        p += __shfl_down(p, off, 64);
    if (lane == 0) fin[slot] = p;
    __syncthreads();
    if (tid == 0)
        out[g] = fin[0] + fin[1] + fin[2] + fin[3] + b_r3[0];
}

extern "C" void kernel_launch(void* const* d_in, const int* in_sizes, int n_in,
                              void* d_out, int out_size, void* d_ws, size_t ws_size,
                              hipStream_t stream)
{
    const float* states_action = (const float*)d_in[0];
    const float* W_msg = (const float*)d_in[1];
    const float* b_msg = (const float*)d_in[2];
    const float* W_gcn = (const float*)d_in[3];
    const float* b_gcn = (const float*)d_in[4];
    const float* W_r1 = (const float*)d_in[5];
    const float* b_r1 = (const float*)d_in[6];
    const float* W_r2 = (const float*)d_in[7];
    const float* b_r2 = (const float*)d_in[8];
    const float* W_r3 = (const float*)d_in[9];
    const float* b_r3 = (const float*)d_in[10];
    const int* gid = (const int*)d_in[11];
    const int* first = (const int*)d_in[12];
    const int* second = (const int*)d_in[13];

    const int n_links = in_sizes[0] / D;     // 100000
    const int n_edges = in_sizes[12];        // 1600000
    const int G = out_size;                  // 256

    const size_t state_bytes = (size_t)n_links * D * sizeof(float);
    char* ws = (char*)d_ws;
    float* S = (float*)ws;                               // 25.6 MB
    float* P = (float*)(ws + state_bytes);               // 25.6 MB
    float* Q = (float*)(ws + 2 * state_bytes);           // 25.6 MB
    char* ws2 = ws + 3 * state_bytes;
    int* counts = (int*)ws2;             ws2 += (size_t)(n_links + 1) * sizeof(int);
    int* row_ptr = (int*)ws2;            ws2 += (size_t)(n_links + 1) * sizeof(int);
    int* cursor = (int*)ws2;             ws2 += (size_t)(n_links + 1) * sizeof(int);
    int* gcounts = (int*)ws2;            ws2 += (size_t)(G + 1) * sizeof(int);
    int* grow = (int*)ws2;               ws2 += (size_t)(G + 1) * sizeof(int);
    int* gcur = (int*)ws2;               ws2 += (size_t)(G + 1) * sizeof(int);
    int* sfirst = (int*)ws2;             ws2 += (size_t)n_edges * sizeof(int);

    // ---- CSR setup (rebuilt every launch; ws is poisoned between runs) ----
    hipMemsetAsync(counts, 0, (size_t)(n_links + 1) * sizeof(int), stream);
    hipMemsetAsync(gcounts, 0, (size_t)(G + 1) * sizeof(int), stream);
    hist_kernel<<<512, 256, 0, stream>>>(second, counts, n_edges);
    hist_kernel<<<512, 256, 0, stream>>>(gid, gcounts, n_links);
    scan_kernel<<<1, 1024, 0, stream>>>(counts, row_ptr, cursor, n_links);
    scan_kernel<<<1, 1024, 0, stream>>>(gcounts, grow, gcur, G);
    scatter_kernel<<<512, 256, 0, stream>>>(first, second, cursor, sfirst, n_edges);

    // ---- T = 4 message-passing iterations ----
    const int edge_blocks = (n_links + 4 * CHUNK - 1) / (4 * CHUNK);  // 12500
    const float* state_in = states_action;
    for (int t = 0; t < 4; ++t) {
        pq_mfma_kernel<<<512, 256, 0, stream>>>(state_in, W_msg, P, Q, n_links);
        edge_link_kernel<<<edge_blocks, 256, 0, stream>>>(P, Q, sfirst, row_ptr,
                                                          b_msg, W_gcn, b_gcn, S, n_links);
        state_in = S;
    }

    // ---- fused readout ----
    readout_kernel<<<G, 256, 0, stream>>>(S, grow, W_r1, b_r1, W_r2, b_r2,
                                          W_r3, b_r3, (float*)d_out);
}